// Round 5
// baseline (343.628 us; speedup 1.0000x reference)
//
#include <hip/hip_runtime.h>
#include <hip/hip_bf16.h>
#include <math.h>

typedef int   v4i __attribute__((ext_vector_type(4)));
typedef float v4f __attribute__((ext_vector_type(4)));

#define B_DIM   256
#define IN_DIM  1024
#define H4      4096
#define NPLANE  4
#define WELEM   (NPLANE * IN_DIM * H4)   // 16777216 per weight tensor
#define XELEM   (B_DIM * IN_DIM)         // 262144

// ---- ws layout ----
// [0,16)        : maxes (w_ih, w_hh, b_ih, b_hh) as float bits (atomicMax on int)
// [64, +4096)   : rowsumX int [4][256]  (per-plane, per-batch-row sums of X bits)
// [WS_X_OFF,..) : X planes int8 [4][256][1024]  (values 0/1)
// [WS_CMP_OFF,) : cmp bytes [2][4][256][4096]
#define WS_RS_OFF     64
#define WS_X_OFF      (64 + 262144)
#define WS_CMP_OFF    (64 + 262144 + 1048576)

// barrier WITHOUT the vmcnt(0) drain __syncthreads() would emit: LDS ordering is
// preserved (lgkmcnt(0) retires all ds_write/ds_read before s_barrier; "memory"
// clobber stops the compiler moving LDS ops across), but global->VGPR prefetch
// loads stay in flight across the barrier (they are wave-private; the compiler's
// own counted vmcnt waits guard their uses).
#define BARRIER_NODRAIN() asm volatile("s_waitcnt lgkmcnt(0)\n\ts_barrier" ::: "memory")

// ---------------- Pass A1: global maxes ----------------
// 2050 blocks (8/CU -> full occupancy) x 4 independent accumulators per lane:
// >= 4 loads in flight per lane, BW-bound instead of latency-bound.
__global__ void k_max(const float* __restrict__ wih, const float* __restrict__ whh,
                      const float* __restrict__ bih, const float* __restrict__ bhh,
                      float* __restrict__ outm) {
  int b = blockIdx.x, t = threadIdx.x;
  float m0 = -3.4e38f, m1 = m0, m2 = m0, m3 = m0;
  if (b < 2048) {
    const float* src = (b < 1024) ? wih : whh;
    int slotb = (b < 1024) ? 0 : 1; (void)slotb;
    const v4f* p = (const v4f*)src;
    const long stride = (long)1024 * 256;          // v4 elements
    long i = (long)(b & 1023) * 256 + t;           // < stride
#pragma unroll
    for (int o = 0; o < 4; ++o) {                  // 16 strided v4 loads total
      v4f v0 = p[i];
      v4f v1 = p[i + stride];
      v4f v2 = p[i + 2 * stride];
      v4f v3 = p[i + 3 * stride];
      m0 = fmaxf(m0, fmaxf(fmaxf(v0.x, v0.y), fmaxf(v0.z, v0.w)));
      m1 = fmaxf(m1, fmaxf(fmaxf(v1.x, v1.y), fmaxf(v1.z, v1.w)));
      m2 = fmaxf(m2, fmaxf(fmaxf(v2.x, v2.y), fmaxf(v2.z, v2.w)));
      m3 = fmaxf(m3, fmaxf(fmaxf(v3.x, v3.y), fmaxf(v3.z, v3.w)));
      i += 4 * stride;
    }
  } else {
    const float* src = (b == 2048) ? bih : bhh;
    const v4f* p = (const v4f*)src;
    for (long i = t; i < 4096; i += 256) {
      v4f v = p[i];
      m0 = fmaxf(m0, fmaxf(fmaxf(v.x, v.y), fmaxf(v.z, v.w)));
    }
  }
  float m = fmaxf(fmaxf(m0, m1), fmaxf(m2, m3));
#pragma unroll
  for (int off = 32; off >= 1; off >>= 1) m = fmaxf(m, __shfl_down(m, off, 64));
  __shared__ float sm[4];
  int w = t >> 6, ln = t & 63;
  if (ln == 0) sm[w] = m;
  __syncthreads();
  if (t == 0) {
    int slot = (b < 1024) ? 0 : (b < 2048) ? 1 : (b == 2048) ? 2 : 3;
    m = fmaxf(fmaxf(sm[0], sm[1]), fmaxf(sm[2], sm[3]));
    atomicMax((int*)&outm[slot], __float_as_int(m));  // maxes are > 0 for gaussian data
  }
}

// ---------------- Pass A2: input bit-planes + per-row bit sums ----------------
__global__ void k_prep(const float* __restrict__ input, const float* __restrict__ a1p,
                       signed char* __restrict__ X, int* __restrict__ rowsum) {
  int tid = threadIdx.x;
  int gid = blockIdx.x * 256 + tid;   // 0..262143
  float a1 = a1p[0];
  float x = input[gid];
  // pact_a exactly as jax: sign(x)*0.5*(|x| - ||x|-a| + a)
  float t = fabsf(x), u = fabsf(t - a1);
  float sg = (x > 0.f) ? 0.5f : ((x < 0.f) ? -0.5f : 0.f);
  float p = sg * ((t - u) + a1);
  float inp01 = (p + a1) / (a1 * 2.0f);
  float q = rintf(15.0f * inp01);              // jnp.round is half-even, matches rintf
  int qi = (int)q;
#pragma unroll
  for (int pl = 0; pl < 4; ++pl)
    X[pl * XELEM + gid] = (signed char)((qi >> (3 - pl)) & 1);

  // per-(plane,row) sums of the bit planes, for the biased-digit correction in k_gemm.
  // pack the 4 plane bits into 4 bytes of one int; per-wave byte sums <= 64, no carry.
  int v = ((qi >> 3) & 1) | (((qi >> 2) & 1) << 8) | (((qi >> 1) & 1) << 16) | ((qi & 1) << 24);
#pragma unroll
  for (int off = 32; off >= 1; off >>= 1) v += __shfl_down(v, off, 64);
  __shared__ int sv[4];
  int wid = tid >> 6, ln = tid & 63;
  if (ln == 0) sv[wid] = v;
  __syncthreads();
  if (tid == 0) {
    int b = blockIdx.x >> 2;   // batch row (1024 cols = 4 blocks per row)
#pragma unroll
    for (int pl = 0; pl < 4; ++pl) {
      int cnt = ((sv[0] >> (8 * pl)) & 255) + ((sv[1] >> (8 * pl)) & 255)
              + ((sv[2] >> (8 * pl)) & 255) + ((sv[3] >> (8 * pl)) & 255);
      atomicAdd(&rowsum[pl * 256 + b], cnt);
    }
  }
}

// ---------------- Pass B: exact digit-GEMM ----------------
// grid: x = ntile (128 tiles of 32 cols), y = sp (s*4 + plane, 8)
// block: 512 threads = 8 waves; wave w covers output rows [w*32, w*32+32)
//
// Digitization (exact): a = w_eff (exact jax f32 chain). n = rintf(a*2^24) is
// exact; provably equal to the nested radix-128 rint chain. m = n + 2^27 in
// [0, 2^28); unsigned base-128 digits u_i = (m >> 7i) & 127 fit signed i8.
// T = sum_i acc_i << (7i) - (rowsumX << 27), identical integer to before.
//
// Staging: v4f global loads (lane = 1 k-row x 4 cols), digitize -> 4 digit
// dwords (byte j = col j), 4x4 byte transpose across lanes {l,l+8,l+16,l+24}
// (2x shfl_xor + 2x v_perm per digit), swizzled dword LDS writes:
//   byte(n, k) at n*64 + ((k>>4) ^ ((n>>1)&3))*16 + (k&15)
// Read side (ds_read_b128 B-fragments) identical to the verified round-1 kernel.
// W/E streams prefetched 2 chunks deep; BARRIER_NODRAIN keeps them in flight
// across the per-chunk barrier (plain __syncthreads drains vmcnt -> was the
// dominant stall: Mfma 15% + VALU 32% + HBM 21%, all idle ~60%).
__global__ __launch_bounds__(512, 2) void k_gemm(
    const float* __restrict__ Wih, const float* __restrict__ Whh,
    const float* __restrict__ Eih, const float* __restrict__ Ehh,
    const float* __restrict__ bih, const float* __restrict__ bhh,
    const float* __restrict__ ebih, const float* __restrict__ ebhh,
    const float* __restrict__ maxm, const int* __restrict__ rowsum,
    const signed char* __restrict__ X, unsigned char* __restrict__ cmp) {
  const int ntile = blockIdx.x;
  const int sp = blockIdx.y;
  const int s = sp >> 2, plane = sp & 3;
  const float* W = s ? Whh : Wih;
  const float* E = s ? Ehh : Eih;
  const float maxw = maxm[s];

  const int tid = threadIdx.x;
  const int wave = tid >> 6, lane = tid & 63, quad = lane >> 4, l15 = lane & 15;

  __shared__ __align__(16) unsigned char Blds[2 * 4 * 32 * 64];   // 16 KB

  // global load mapping: k-row kl (0..63 within chunk), cols nc4..nc4+3
  const int kl  = tid >> 3;          // 8 rows per wave
  const int nc4 = (tid & 7) << 2;
  // transpose-group position: lanes {l0, l0+8, l0+16, l0+24} hold rows p=0..3
  const int p  = (lane >> 3) & 3;
  const int sq = p & 1, qq = p >> 1;
  const unsigned sel1 = sq ? 0x03070206u : 0x05010400u;
  const unsigned sel2 = qq ? 0x03020706u : 0x05040100u;
  // post-transpose write coords: column snW, k-dword kqW
  const int snW = nc4 + 2 * sq + qq;            // 0..31, bijective per half-wave
  const int kqW = (wave << 1) + (lane >> 5);    // 0..15
  const int wr_off = snW * 64 + ((((kqW >> 2) ^ ((snW >> 1) & 3)) << 4) | ((kqW & 3) << 2));

  v4i acc[4][2][2];
#pragma unroll
  for (int d = 0; d < 4; ++d)
#pragma unroll
    for (int m = 0; m < 2; ++m)
#pragma unroll
      for (int n = 0; n < 2; ++n) acc[d][m][n] = (v4i){0, 0, 0, 0};

  const size_t cstep = (size_t)64 * H4;  // chunk stride (floats)
  const float* wp = W + ((size_t)plane * IN_DIM + kl) * H4 + (size_t)ntile * 32 + nc4;
  const float* ep = E + ((size_t)plane * IN_DIM + kl) * H4 + (size_t)ntile * 32 + nc4;

  const signed char* Xp = X + plane * XELEM;
  const int arow0 = wave * 32 + l15;

  // digitize 4 elements (cols nc4..+3 at row kl) -> 4 digit dwords (byte j = col j)
  auto digitize4 = [&](v4f w4, v4f e4, unsigned pk[4]) {
    int mm[4];
#pragma unroll
    for (int j = 0; j < 4; ++j) {
      float w = w4[j], ev = e4[j];
      float xc = fminf(fmaxf(w, -0.9921875f), 0.9921875f);
      float qv = rintf(xc * 128.f) * 0.0078125f;
      float noise = (ev * maxw) * 0.1f;
      float a = w + ((qv - w) + noise);          // exact jax f32 chain -> w_eff
      mm[j] = (int)rintf(a * 16777216.0f) + (1 << 27);   // biased, in [0, 2^28)
    }
#pragma unroll
    for (int d = 0; d < 4; ++d) {
      const int sh = 21 - 7 * d;
      unsigned a0 = (unsigned)(mm[0] >> sh);
      unsigned a1 = (unsigned)(mm[1] >> sh);
      unsigned a2 = (unsigned)(mm[2] >> sh);
      unsigned a3 = (unsigned)(mm[3] >> sh);
      unsigned t1 = __builtin_amdgcn_perm(a1, a0, 0x00000400u);  // [a0.b0, a1.b0, ., .]
      unsigned t2 = __builtin_amdgcn_perm(a3, a2, 0x00000400u);  // [a2.b0, a3.b0, ., .]
      pk[d] = __builtin_amdgcn_perm(t2, t1, 0x05040100u) & 0x7f7f7f7fu;
    }
  };
  // 4x4 byte transpose across lanes {^8, ^16}, then swizzled dword write
  auto transpose_write = [&](const unsigned pk[4], int bf) {
    unsigned char* base = Blds + bf * 8192 + wr_off;
#pragma unroll
    for (int d = 0; d < 4; ++d) {
      unsigned A = pk[d];
      unsigned t = (unsigned)__shfl_xor((int)A, 8, 64);
      unsigned D = __builtin_amdgcn_perm(t, A, sel1);    // cols {2s,2s+1}, rows {2q,2q+1}
      unsigned Ex = (unsigned)__shfl_xor((int)D, 16, 64);
      unsigned o = __builtin_amdgcn_perm(Ex, D, sel2);   // column 2s+q, rows 0..3
      *(unsigned*)(base + d * 2048) = o;
    }
  };

  // ---- prologue ----
  unsigned pk[4];
  {
    v4f w4 = *(const v4f*)wp;
    v4f e4 = *(const v4f*)ep;
    digitize4(w4, e4, pk);
    transpose_write(pk, 0);
  }
  v4f wA = *(const v4f*)(wp + cstep);    // chunk 1 in flight
  v4f eA = *(const v4f*)(ep + cstep);
  v4i afr[2];
  afr[0] = *(const v4i*)(Xp + (arow0) * IN_DIM + quad * 16);
  afr[1] = *(const v4i*)(Xp + (arow0 + 16) * IN_DIM + quad * 16);
  BARRIER_NODRAIN();

  for (int ch = 0; ch < 16; ++ch) {
    const int buf = ch & 1;
    // issue chunk ch+2 W/E loads (2-deep) and chunk ch+1 X loads (1-deep)
    v4f wB = wA, eB = eA;
    v4i anx0 = afr[0], anx1 = afr[1];
    if (ch < 14) {
      wB = *(const v4f*)(wp + (size_t)(ch + 2) * cstep);
      eB = *(const v4f*)(ep + (size_t)(ch + 2) * cstep);
    }
    if (ch < 15) {
      anx0 = *(const v4i*)(Xp + (arow0) * IN_DIM + (ch + 1) * 64 + quad * 16);
      anx1 = *(const v4i*)(Xp + (arow0 + 16) * IN_DIM + (ch + 1) * 64 + quad * 16);
    }
    // MFMA on current buffer
    const unsigned char* rb = Blds + buf * 8192;
#pragma unroll
    for (int d = 0; d < 4; ++d) {
#pragma unroll
      for (int ns = 0; ns < 2; ++ns) {
        const int nr = ns * 16 + l15;
        v4i bfr = *(const v4i*)(rb + d * 2048 + nr * 64 + ((quad ^ ((nr >> 1) & 3)) << 4));
        acc[d][0][ns] = __builtin_amdgcn_mfma_i32_16x16x64_i8(afr[0], bfr, acc[d][0][ns], 0, 0, 0);
        acc[d][1][ns] = __builtin_amdgcn_mfma_i32_16x16x64_i8(afr[1], bfr, acc[d][1][ns], 0, 0, 0);
      }
    }
    // digitize chunk ch+1 (its loads have been in flight a full iteration)
    if (ch < 15) {
      digitize4(wA, eA, pk);
      transpose_write(pk, buf ^ 1);
      wA = wB; eA = eB;
    }
    afr[0] = anx0; afr[1] = anx1;
    BARRIER_NODRAIN();
  }

  // ---- epilogue: inline threshold + exact combine + compare ----
  const float* bp  = s ? bhh : bih;
  const float* ebp = s ? ebhh : ebih;
  const float mb = maxm[2 + s];
  const int* rs = rowsum + plane * 256;
  const double inv = 1.0 / 16777216.0;   // /(8*128^3)
  unsigned char* cp = cmp + (size_t)sp * B_DIM * H4;
#pragma unroll
  for (int ns = 0; ns < 2; ++ns) {
    int col = ntile * 32 + ns * 16 + l15;
    float bv = bp[plane * H4 + col], ev = ebp[plane * H4 + col];
    float xc = fminf(fmaxf(bv, -0.9921875f), 0.9921875f);
    float qv = rintf(xc * 128.f) * 0.0078125f;
    float noise = (ev * mb) * 0.1f;
    float beff = bv + ((qv - bv) + noise);
    double th = 0.5 - (double)beff;
#pragma unroll
    for (int ms = 0; ms < 2; ++ms) {
#pragma unroll
      for (int r = 0; r < 4; ++r) {
        int row = wave * 32 + ms * 16 + quad * 4 + r;
        long long T = ((long long)acc[0][ms][ns][r] << 21) + ((long long)acc[1][ms][ns][r] << 14)
                    + ((long long)acc[2][ms][ns][r] << 7)  +  (long long)acc[3][ms][ns][r]
                    - ((long long)rs[row] << 27);          // remove digit bias
        cp[(size_t)row * H4 + col] = ((double)T * inv > th) ? 1 : 0;
      }
    }
  }
}

// ---------------- Pass C: pointwise LSTM ----------------
__device__ __forceinline__ float pact_(float x, float a) {
  float t = fabsf(x), u = fabsf(t - a);
  float sg = (x > 0.f) ? 0.5f : ((x < 0.f) ? -0.5f : 0.f);
  return sg * ((t - u) + a);
}
__device__ __forceinline__ float quant_(float x, float a) {
  float xr = x / a;
  xr = fminf(fmaxf(xr, -0.9921875f), 0.9921875f);
  return rintf(xr * 128.f) * 0.0078125f * a;
}
__device__ __forceinline__ float sigm_(float x) { return 1.0f / (1.0f + expf(-x)); }

__global__ void k_pointwise(const unsigned char* __restrict__ cmp, const float* __restrict__ cx,
                            const float* a3, const float* a4, const float* a5, const float* a6,
                            const float* a7, const float* a8, const float* a9, const float* a10,
                            const float* a11, float* __restrict__ out) {
  int idx = blockIdx.x * 256 + threadIdx.x;   // 0..262143
  int b = idx >> 10, h = idx & 1023;
  float g[4];
#pragma unroll
  for (int gi = 0; gi < 4; ++gi) {
    int col = gi * 1024 + h;
    float acc = 0.f;
#pragma unroll
    for (int n = 0; n < 4; ++n) {
      int o = (int)cmp[((size_t)(0 * 4 + n) * B_DIM + b) * H4 + col]
            + (int)cmp[((size_t)(1 * 4 + n) * B_DIM + b) * H4 + col];
      float beta = (float)(8 >> n) / 15.0f;
      acc = acc + beta * (float)o;
    }
    g[gi] = acc;
  }
  float fg = quant_(pact_(sigm_(g[2]), a3[0]), a3[0]);
  float ig = quant_(pact_(sigm_(g[0]), a4[0]), a4[0]);
  float ac = quant_(pact_(tanhf(g[1]), a5[0]), a5[0]);
  float og = quant_(pact_(sigm_(g[3]), a6[0]), a6[0]);
  float cxv = cx[idx];
  float gc = quant_(pact_(cxv * fg, a7[0]), a7[0]);
  float ai = quant_(pact_(ig * ac, a8[0]), a8[0]);
  float nc = quant_(pact_(gc + ai, a9[0]), a9[0]);
  float acl = quant_(pact_(tanhf(nc), a10[0]), a10[0]);
  float nh = quant_(pact_(acl * og, a11[0]), a11[0]);
  out[idx] = nh;
  out[XELEM + idx] = nc;
}

extern "C" void kernel_launch(void* const* d_in, const int* in_sizes, int n_in,
                              void* d_out, int out_size, void* d_ws, size_t ws_size,
                              hipStream_t stream) {
  (void)in_sizes; (void)n_in; (void)out_size; (void)ws_size;
  const float* input = (const float*)d_in[0];
  const float* cx    = (const float*)d_in[2];
  const float* wih   = (const float*)d_in[3];
  const float* whh   = (const float*)d_in[4];
  const float* bih   = (const float*)d_in[5];
  const float* bhh   = (const float*)d_in[6];
  const float* ewih  = (const float*)d_in[7];
  const float* ewhh  = (const float*)d_in[8];
  const float* ebih  = (const float*)d_in[9];
  const float* ebhh  = (const float*)d_in[10];
  const float* a1    = (const float*)d_in[11];
  const float* a3    = (const float*)d_in[12];
  const float* a4    = (const float*)d_in[13];
  const float* a5    = (const float*)d_in[14];
  const float* a6    = (const float*)d_in[15];
  const float* a7    = (const float*)d_in[16];
  const float* a8    = (const float*)d_in[17];
  const float* a9    = (const float*)d_in[18];
  const float* a10   = (const float*)d_in[19];
  const float* a11   = (const float*)d_in[20];
  float* out = (float*)d_out;

  char* ws = (char*)d_ws;
  float*         maxm   = (float*)ws;
  int*           rowsum = (int*)(ws + WS_RS_OFF);
  signed char*   X      = (signed char*)(ws + WS_X_OFF);
  unsigned char* cmp    = (unsigned char*)(ws + WS_CMP_OFF);

  hipMemsetAsync(ws, 0, 64 + 4096, stream);
  k_max<<<2050, 256, 0, stream>>>(wih, whh, bih, bhh, maxm);
  k_prep<<<1024, 256, 0, stream>>>(input, a1, X, rowsum);
  k_gemm<<<dim3(128, 8), 512, 0, stream>>>(wih, whh, ewih, ewhh, bih, bhh, ebih, ebhh,
                                           maxm, rowsum, X, cmp);
  k_pointwise<<<1024, 256, 0, stream>>>(cmp, cx, a3, a4, a5, a6, a7, a8, a9, a10, a11, out);
}

// Round 6
// 337.157 us; speedup vs baseline: 1.0192x; 1.0192x over previous
//
#include <hip/hip_runtime.h>
#include <hip/hip_bf16.h>
#include <math.h>

typedef int   v4i __attribute__((ext_vector_type(4)));
typedef float v4f __attribute__((ext_vector_type(4)));

#define B_DIM   256
#define IN_DIM  1024
#define H4      4096
#define NPLANE  4
#define WELEM   (NPLANE * IN_DIM * H4)   // 16777216 per weight tensor
#define XELEM   (B_DIM * IN_DIM)         // 262144

// ---- ws layout ----
// [0,16)        : maxes (w_ih, w_hh, b_ih, b_hh) as float bits (atomicMax on int)
// [64, +4096)   : rowsumX int [4][256]  (per-plane, per-batch-row sums of X bits)
// [WS_X_OFF,..) : X planes int8 [4][256][1024]  (values 0/1)
// [WS_CMP_OFF,) : cmp bytes [2][4][256][4096]
#define WS_RS_OFF     64
#define WS_X_OFF      (64 + 262144)
#define WS_CMP_OFF    (64 + 262144 + 1048576)

// ---------------- Pass A1: global maxes ----------------
// 2050 blocks x 4 independent accumulators per lane: >=4 loads in flight,
// BW-bound instead of latency-bound.
__global__ void k_max(const float* __restrict__ wih, const float* __restrict__ whh,
                      const float* __restrict__ bih, const float* __restrict__ bhh,
                      float* __restrict__ outm) {
  int b = blockIdx.x, t = threadIdx.x;
  float m0 = -3.4e38f, m1 = m0, m2 = m0, m3 = m0;
  if (b < 2048) {
    const float* src = (b < 1024) ? wih : whh;
    const v4f* p = (const v4f*)src;
    const long stride = (long)1024 * 256;          // v4 elements
    long i = (long)(b & 1023) * 256 + t;           // < stride
#pragma unroll
    for (int o = 0; o < 4; ++o) {                  // 16 strided v4 loads total
      v4f v0 = p[i];
      v4f v1 = p[i + stride];
      v4f v2 = p[i + 2 * stride];
      v4f v3 = p[i + 3 * stride];
      m0 = fmaxf(m0, fmaxf(fmaxf(v0.x, v0.y), fmaxf(v0.z, v0.w)));
      m1 = fmaxf(m1, fmaxf(fmaxf(v1.x, v1.y), fmaxf(v1.z, v1.w)));
      m2 = fmaxf(m2, fmaxf(fmaxf(v2.x, v2.y), fmaxf(v2.z, v2.w)));
      m3 = fmaxf(m3, fmaxf(fmaxf(v3.x, v3.y), fmaxf(v3.z, v3.w)));
      i += 4 * stride;
    }
  } else {
    const float* src = (b == 2048) ? bih : bhh;
    const v4f* p = (const v4f*)src;
    for (long i = t; i < 4096; i += 256) {
      v4f v = p[i];
      m0 = fmaxf(m0, fmaxf(fmaxf(v.x, v.y), fmaxf(v.z, v.w)));
    }
  }
  float m = fmaxf(fmaxf(m0, m1), fmaxf(m2, m3));
#pragma unroll
  for (int off = 32; off >= 1; off >>= 1) m = fmaxf(m, __shfl_down(m, off, 64));
  __shared__ float sm[4];
  int w = t >> 6, ln = t & 63;
  if (ln == 0) sm[w] = m;
  __syncthreads();
  if (t == 0) {
    int slot = (b < 1024) ? 0 : (b < 2048) ? 1 : (b == 2048) ? 2 : 3;
    m = fmaxf(fmaxf(sm[0], sm[1]), fmaxf(sm[2], sm[3]));
    atomicMax((int*)&outm[slot], __float_as_int(m));  // maxes are > 0 for gaussian data
  }
}

// ---------------- Pass A2: input bit-planes + per-row bit sums ----------------
__global__ void k_prep(const float* __restrict__ input, const float* __restrict__ a1p,
                       signed char* __restrict__ X, int* __restrict__ rowsum) {
  int tid = threadIdx.x;
  int gid = blockIdx.x * 256 + tid;   // 0..262143
  float a1 = a1p[0];
  float x = input[gid];
  // pact_a exactly as jax: sign(x)*0.5*(|x| - ||x|-a| + a)
  float t = fabsf(x), u = fabsf(t - a1);
  float sg = (x > 0.f) ? 0.5f : ((x < 0.f) ? -0.5f : 0.f);
  float p = sg * ((t - u) + a1);
  float inp01 = (p + a1) / (a1 * 2.0f);
  float q = rintf(15.0f * inp01);              // jnp.round is half-even, matches rintf
  int qi = (int)q;
#pragma unroll
  for (int pl = 0; pl < 4; ++pl)
    X[pl * XELEM + gid] = (signed char)((qi >> (3 - pl)) & 1);

  // per-(plane,row) sums of the bit planes, for the biased-digit correction in k_gemm.
  // pack the 4 plane bits into 4 bytes of one int; per-wave byte sums <= 64, no carry.
  int v = ((qi >> 3) & 1) | (((qi >> 2) & 1) << 8) | (((qi >> 1) & 1) << 16) | ((qi & 1) << 24);
#pragma unroll
  for (int off = 32; off >= 1; off >>= 1) v += __shfl_down(v, off, 64);
  __shared__ int sv[4];
  int wid = tid >> 6, ln = tid & 63;
  if (ln == 0) sv[wid] = v;
  __syncthreads();
  if (tid == 0) {
    int b = blockIdx.x >> 2;   // batch row (1024 cols = 4 blocks per row)
#pragma unroll
    for (int pl = 0; pl < 4; ++pl) {
      int cnt = ((sv[0] >> (8 * pl)) & 255) + ((sv[1] >> (8 * pl)) & 255)
              + ((sv[2] >> (8 * pl)) & 255) + ((sv[3] >> (8 * pl)) & 255);
      atomicAdd(&rowsum[pl * 256 + b], cnt);
    }
  }
}

// ---------------- Pass B: exact digit-GEMM (round-4 state, the measured best) ----
// grid: x = ntile (128 tiles of 32 cols), y = sp (s*4 + plane, 8)
// block: 512 threads = 8 waves; wave w covers output rows [w*32, w*32+32)
//
// Occupancy note: acc = 64 AGPR + ~60 VGPR = 124 regs -> 2 blocks/CU is the
// structural cap. Inline-asm barrier variants cost +8 VGPR (crossing the 64-reg
// step, occ 35%->21%, +18us) -- keep plain __syncthreads().
__global__ __launch_bounds__(512, 2) void k_gemm(
    const float* __restrict__ Wih, const float* __restrict__ Whh,
    const float* __restrict__ Eih, const float* __restrict__ Ehh,
    const float* __restrict__ bih, const float* __restrict__ bhh,
    const float* __restrict__ ebih, const float* __restrict__ ebhh,
    const float* __restrict__ maxm, const int* __restrict__ rowsum,
    const signed char* __restrict__ X, unsigned char* __restrict__ cmp) {
  const int ntile = blockIdx.x;
  const int sp = blockIdx.y;
  const int s = sp >> 2, plane = sp & 3;
  const float* W = s ? Whh : Wih;
  const float* E = s ? Ehh : Eih;
  const float maxw = maxm[s];

  const int tid = threadIdx.x;
  const int wave = tid >> 6, lane = tid & 63, quad = lane >> 4, l15 = lane & 15;

  __shared__ __align__(16) unsigned char Blds[2 * 4 * 32 * 64];   // 16 KB

  // global load mapping: k-row kl (0..63 within chunk), cols nc4..nc4+3
  const int kl  = tid >> 3;          // 8 rows per wave
  const int nc4 = (tid & 7) << 2;
  // transpose-group position: lanes {l0, l0+8, l0+16, l0+24} hold rows p=0..3
  const int p  = (lane >> 3) & 3;
  const int sq = p & 1, qq = p >> 1;
  const unsigned sel1 = sq ? 0x03070206u : 0x05010400u;
  const unsigned sel2 = qq ? 0x03020706u : 0x05040100u;
  // post-transpose write coords: column snW, k-dword kqW
  const int snW = nc4 + 2 * sq + qq;            // 0..31, bijective per half-wave
  const int kqW = (wave << 1) + (lane >> 5);    // 0..15
  const int wr_off = snW * 64 + ((((kqW >> 2) ^ ((snW >> 1) & 3)) << 4) | ((kqW & 3) << 2));

  v4i acc[4][2][2];
#pragma unroll
  for (int d = 0; d < 4; ++d)
#pragma unroll
    for (int m = 0; m < 2; ++m)
#pragma unroll
      for (int n = 0; n < 2; ++n) acc[d][m][n] = (v4i){0, 0, 0, 0};

  const size_t cstep = (size_t)64 * H4;  // chunk stride (floats)
  const float* wp = W + ((size_t)plane * IN_DIM + kl) * H4 + (size_t)ntile * 32 + nc4;
  const float* ep = E + ((size_t)plane * IN_DIM + kl) * H4 + (size_t)ntile * 32 + nc4;

  const signed char* Xp = X + plane * XELEM;
  const int arow0 = wave * 32 + l15;

  // digitize 4 elements (cols nc4..+3 at row kl) -> 4 digit dwords (byte j = col j)
  auto digitize4 = [&](v4f w4, v4f e4, unsigned pk[4]) {
    int mm[4];
#pragma unroll
    for (int j = 0; j < 4; ++j) {
      float w = w4[j], ev = e4[j];
      float xc = fminf(fmaxf(w, -0.9921875f), 0.9921875f);
      float qv = rintf(xc * 128.f) * 0.0078125f;
      float noise = (ev * maxw) * 0.1f;
      float a = w + ((qv - w) + noise);          // exact jax f32 chain -> w_eff
      mm[j] = (int)rintf(a * 16777216.0f) + (1 << 27);   // biased, in [0, 2^28)
    }
#pragma unroll
    for (int d = 0; d < 4; ++d) {
      const int sh = 21 - 7 * d;
      unsigned a0 = (unsigned)(mm[0] >> sh);
      unsigned a1 = (unsigned)(mm[1] >> sh);
      unsigned a2 = (unsigned)(mm[2] >> sh);
      unsigned a3 = (unsigned)(mm[3] >> sh);
      unsigned t1 = __builtin_amdgcn_perm(a1, a0, 0x00000400u);  // [a0.b0, a1.b0, ., .]
      unsigned t2 = __builtin_amdgcn_perm(a3, a2, 0x00000400u);  // [a2.b0, a3.b0, ., .]
      pk[d] = __builtin_amdgcn_perm(t2, t1, 0x05040100u) & 0x7f7f7f7fu;
    }
  };
  // 4x4 byte transpose across lanes {^8, ^16}, then swizzled dword write
  auto transpose_write = [&](const unsigned pk[4], int bf) {
    unsigned char* base = Blds + bf * 8192 + wr_off;
#pragma unroll
    for (int d = 0; d < 4; ++d) {
      unsigned A = pk[d];
      unsigned t = (unsigned)__shfl_xor((int)A, 8, 64);
      unsigned D = __builtin_amdgcn_perm(t, A, sel1);    // cols {2s,2s+1}, rows {2q,2q+1}
      unsigned Ex = (unsigned)__shfl_xor((int)D, 16, 64);
      unsigned o = __builtin_amdgcn_perm(Ex, D, sel2);   // column 2s+q, rows 0..3
      *(unsigned*)(base + d * 2048) = o;
    }
  };

  // ---- prologue ----
  unsigned pk[4];
  {
    v4f w4 = *(const v4f*)wp;
    v4f e4 = *(const v4f*)ep;
    digitize4(w4, e4, pk);
    transpose_write(pk, 0);
  }
  v4f wA = *(const v4f*)(wp + cstep);    // chunk 1 in flight
  v4f eA = *(const v4f*)(ep + cstep);
  v4i afr[2];
  afr[0] = *(const v4i*)(Xp + (arow0) * IN_DIM + quad * 16);
  afr[1] = *(const v4i*)(Xp + (arow0 + 16) * IN_DIM + quad * 16);
  __syncthreads();

  for (int ch = 0; ch < 16; ++ch) {
    const int buf = ch & 1;
    // issue chunk ch+2 W/E loads (2-deep) and chunk ch+1 X loads (1-deep)
    v4f wB = wA, eB = eA;
    v4i anx0 = afr[0], anx1 = afr[1];
    if (ch < 14) {
      wB = *(const v4f*)(wp + (size_t)(ch + 2) * cstep);
      eB = *(const v4f*)(ep + (size_t)(ch + 2) * cstep);
    }
    if (ch < 15) {
      anx0 = *(const v4i*)(Xp + (arow0) * IN_DIM + (ch + 1) * 64 + quad * 16);
      anx1 = *(const v4i*)(Xp + (arow0 + 16) * IN_DIM + (ch + 1) * 64 + quad * 16);
    }
    // MFMA on current buffer
    const unsigned char* rb = Blds + buf * 8192;
#pragma unroll
    for (int d = 0; d < 4; ++d) {
#pragma unroll
      for (int ns = 0; ns < 2; ++ns) {
        const int nr = ns * 16 + l15;
        v4i bfr = *(const v4i*)(rb + d * 2048 + nr * 64 + ((quad ^ ((nr >> 1) & 3)) << 4));
        acc[d][0][ns] = __builtin_amdgcn_mfma_i32_16x16x64_i8(afr[0], bfr, acc[d][0][ns], 0, 0, 0);
        acc[d][1][ns] = __builtin_amdgcn_mfma_i32_16x16x64_i8(afr[1], bfr, acc[d][1][ns], 0, 0, 0);
      }
    }
    // digitize chunk ch+1 (its loads have been in flight a full iteration)
    if (ch < 15) {
      digitize4(wA, eA, pk);
      transpose_write(pk, buf ^ 1);
      wA = wB; eA = eB;
    }
    afr[0] = anx0; afr[1] = anx1;
    __syncthreads();
  }

  // ---- epilogue: inline threshold + exact combine + compare ----
  const float* bp  = s ? bhh : bih;
  const float* ebp = s ? ebhh : ebih;
  const float mb = maxm[2 + s];
  const int* rs = rowsum + plane * 256;
  const double inv = 1.0 / 16777216.0;   // /(8*128^3)
  unsigned char* cp = cmp + (size_t)sp * B_DIM * H4;
#pragma unroll
  for (int ns = 0; ns < 2; ++ns) {
    int col = ntile * 32 + ns * 16 + l15;
    float bv = bp[plane * H4 + col], ev = ebp[plane * H4 + col];
    float xc = fminf(fmaxf(bv, -0.9921875f), 0.9921875f);
    float qv = rintf(xc * 128.f) * 0.0078125f;
    float noise = (ev * mb) * 0.1f;
    float beff = bv + ((qv - bv) + noise);
    double th = 0.5 - (double)beff;
#pragma unroll
    for (int ms = 0; ms < 2; ++ms) {
#pragma unroll
      for (int r = 0; r < 4; ++r) {
        int row = wave * 32 + ms * 16 + quad * 4 + r;
        long long T = ((long long)acc[0][ms][ns][r] << 21) + ((long long)acc[1][ms][ns][r] << 14)
                    + ((long long)acc[2][ms][ns][r] << 7)  +  (long long)acc[3][ms][ns][r]
                    - ((long long)rs[row] << 27);          // remove digit bias
        cp[(size_t)row * H4 + col] = ((double)T * inv > th) ? 1 : 0;
      }
    }
  }
}

// ---------------- Pass C: pointwise LSTM (vectorized 4h/thread) ----------------
// Old version: 32 x 1-byte global loads per output element = 131k vmem instrs
// per dispatch at 64 B/wave -- vmem-issue bound. Now each thread handles 4
// consecutive h via dword cmp loads (4x fewer instrs, 256 B/wave), v4f cx/out.
// Per-element float arithmetic is IDENTICAL (same n-order, same beta chain).
__device__ __forceinline__ float pact_(float x, float a) {
  float t = fabsf(x), u = fabsf(t - a);
  float sg = (x > 0.f) ? 0.5f : ((x < 0.f) ? -0.5f : 0.f);
  return sg * ((t - u) + a);
}
__device__ __forceinline__ float quant_(float x, float a) {
  float xr = x / a;
  xr = fminf(fmaxf(xr, -0.9921875f), 0.9921875f);
  return rintf(xr * 128.f) * 0.0078125f * a;
}
__device__ __forceinline__ float sigm_(float x) { return 1.0f / (1.0f + expf(-x)); }

__global__ void k_pointwise(const unsigned char* __restrict__ cmp, const float* __restrict__ cx,
                            const float* a3, const float* a4, const float* a5, const float* a6,
                            const float* a7, const float* a8, const float* a9, const float* a10,
                            const float* a11, float* __restrict__ out) {
  int t4 = blockIdx.x * 256 + threadIdx.x;   // 0..65535, 4 h-values each
  int b = t4 >> 8;                            // 0..255
  int h4 = (t4 & 255) << 2;                   // 0..1020
  float g[4][4];                              // [gi][j]
#pragma unroll
  for (int gi = 0; gi < 4; ++gi) {
    float a0 = 0.f, a1 = 0.f, a2 = 0.f, a3v = 0.f;
#pragma unroll
    for (int n = 0; n < 4; ++n) {
      unsigned d0 = *(const unsigned*)(cmp + (((size_t)(0 * 4 + n) * B_DIM + b) << 12) + gi * 1024 + h4);
      unsigned d1 = *(const unsigned*)(cmp + (((size_t)(1 * 4 + n) * B_DIM + b) << 12) + gi * 1024 + h4);
      float beta = (float)(8 >> n) / 15.0f;
      a0  += beta * (float)((int)(d0 & 255u)         + (int)(d1 & 255u));
      a1  += beta * (float)((int)((d0 >> 8) & 255u)  + (int)((d1 >> 8) & 255u));
      a2  += beta * (float)((int)((d0 >> 16) & 255u) + (int)((d1 >> 16) & 255u));
      a3v += beta * (float)((int)(d0 >> 24)          + (int)(d1 >> 24));
    }
    g[gi][0] = a0; g[gi][1] = a1; g[gi][2] = a2; g[gi][3] = a3v;
  }
  int idx = b * 1024 + h4;
  v4f cxv = *(const v4f*)(cx + idx);
  v4f nhv, ncv;
  float va3 = a3[0], va4 = a4[0], va5 = a5[0], va6 = a6[0], va7 = a7[0];
  float va8 = a8[0], va9 = a9[0], va10 = a10[0], va11 = a11[0];
#pragma unroll
  for (int j = 0; j < 4; ++j) {
    float fg = quant_(pact_(sigm_(g[2][j]), va3), va3);
    float ig = quant_(pact_(sigm_(g[0][j]), va4), va4);
    float ac = quant_(pact_(tanhf(g[1][j]), va5), va5);
    float og = quant_(pact_(sigm_(g[3][j]), va6), va6);
    float gc = quant_(pact_(cxv[j] * fg, va7), va7);
    float ai = quant_(pact_(ig * ac, va8), va8);
    float nc = quant_(pact_(gc + ai, va9), va9);
    float acl = quant_(pact_(tanhf(nc), va10), va10);
    float nh = quant_(pact_(acl * og, va11), va11);
    nhv[j] = nh; ncv[j] = nc;
  }
  *(v4f*)(out + idx) = nhv;
  *(v4f*)(out + XELEM + idx) = ncv;
}

extern "C" void kernel_launch(void* const* d_in, const int* in_sizes, int n_in,
                              void* d_out, int out_size, void* d_ws, size_t ws_size,
                              hipStream_t stream) {
  (void)in_sizes; (void)n_in; (void)out_size; (void)ws_size;
  const float* input = (const float*)d_in[0];
  const float* cx    = (const float*)d_in[2];
  const float* wih   = (const float*)d_in[3];
  const float* whh   = (const float*)d_in[4];
  const float* bih   = (const float*)d_in[5];
  const float* bhh   = (const float*)d_in[6];
  const float* ewih  = (const float*)d_in[7];
  const float* ewhh  = (const float*)d_in[8];
  const float* ebih  = (const float*)d_in[9];
  const float* ebhh  = (const float*)d_in[10];
  const float* a1    = (const float*)d_in[11];
  const float* a3    = (const float*)d_in[12];
  const float* a4    = (const float*)d_in[13];
  const float* a5    = (const float*)d_in[14];
  const float* a6    = (const float*)d_in[15];
  const float* a7    = (const float*)d_in[16];
  const float* a8    = (const float*)d_in[17];
  const float* a9    = (const float*)d_in[18];
  const float* a10   = (const float*)d_in[19];
  const float* a11   = (const float*)d_in[20];
  float* out = (float*)d_out;

  char* ws = (char*)d_ws;
  float*         maxm   = (float*)ws;
  int*           rowsum = (int*)(ws + WS_RS_OFF);
  signed char*   X      = (signed char*)(ws + WS_X_OFF);
  unsigned char* cmp    = (unsigned char*)(ws + WS_CMP_OFF);

  hipMemsetAsync(ws, 0, 64 + 4096, stream);
  k_max<<<2050, 256, 0, stream>>>(wih, whh, bih, bhh, maxm);
  k_prep<<<1024, 256, 0, stream>>>(input, a1, X, rowsum);
  k_gemm<<<dim3(128, 8), 512, 0, stream>>>(wih, whh, ewih, ewhh, bih, bhh, ebih, ebhh,
                                           maxm, rowsum, X, cmp);
  k_pointwise<<<256, 256, 0, stream>>>(cmp, cx, a3, a4, a5, a6, a7, a8, a9, a10, a11, out);
}